// Round 1
// baseline (9723.522 us; speedup 1.0000x reference)
//
#include <hip/hip_runtime.h>

// ---------------- constants ----------------
// B=256, PH=14 -> P=196, ENC=2048, V=10000, E=512, H=512, A=512, S=54, T=53
#define NB   256
#define NP   196
#define NENC 2048
#define NV   10000
#define NE   512
#define NH   512
#define NS   54
#define NT   53
#define NIN  3072      // [x(512) | ctx(2048) | h(512)]
#define NG   2048      // 4*H
#define NHS  2560      // [hid_att(512) | sag_pre(2048)]

typedef __bf16 bf16x8 __attribute__((ext_vector_type(8)));
typedef float  f32x4  __attribute__((ext_vector_type(4)));

__device__ __forceinline__ float bf_lo(unsigned u){ union{unsigned i; float f;} v; v.i = u << 16; return v.f; }
__device__ __forceinline__ float bf_hi(unsigned u){ union{unsigned i; float f;} v; v.i = u & 0xffff0000u; return v.f; }
__device__ __forceinline__ float bf2f(unsigned short s){ union{unsigned i; float f;} v; v.i = ((unsigned)s) << 16; return v.f; }
__device__ __forceinline__ unsigned short f2bf(float f){
    union{float f; unsigned u;} v; v.f = f;
    unsigned r = v.u + 0x7fffu + ((v.u >> 16) & 1u);
    return (unsigned short)(r >> 16);
}
__device__ __forceinline__ float sigf(float x){ return 1.f / (1.f + __expf(-x)); }

// ---------------- sort / lengths / caps ----------------
__global__ void k_sort(const int* __restrict__ cap_len, const int* __restrict__ captions,
                       int* __restrict__ order, int* __restrict__ act_cnt,
                       int* __restrict__ caps_s, float* __restrict__ out_predlen,
                       float* __restrict__ out_caps)
{
    __shared__ int lens[NB];
    __shared__ int ord[NB];
    __shared__ int pls[NB];
    int b = threadIdx.x;
    lens[b] = cap_len[b];
    __syncthreads();
    int L = lens[b];
    int rank = 0;
    for (int j = 0; j < NB; j++) {
        int Lj = lens[j];
        rank += (Lj > L) || (Lj == L && j < b);
    }
    ord[rank] = b;
    __syncthreads();
    int src = ord[b];
    order[b] = src;
    int pl = lens[src] - 1;
    pls[b] = pl;
    out_predlen[b] = (float)pl;
    for (int s = 0; s < NS; s++) {
        int c = captions[src * NS + s];
        caps_s[b * NS + s] = c;
        out_caps[b * NS + s] = (float)c;
    }
    __syncthreads();
    if (b < NT) {
        int cnt = 0;
        for (int j = 0; j < NB; j++) cnt += (pls[j] > b);
        act_cnt[b] = cnt;
    }
}

// ---------------- bias prep ----------------
__global__ void k_bias(const float* b_ih, const float* b_hh, const float* att_h_b,
                       const float* sag_b, const float* eh_b, const float* ec_b,
                       float* bg, float* hsb, float* hcb)
{
    int i = blockIdx.x * 256 + threadIdx.x;
    if (i < NG)  bg[i] = b_ih[i] + b_hh[i];
    if (i < NH)  hsb[i] = att_h_b[i];
    if (i >= NH && i < NHS) hsb[i] = sag_b[i - NH];
    if (i < NH)  hcb[i] = eh_b[i];
    if (i >= NH && i < 2 * NH) hcb[i] = ec_b[i - NH];
}

// ---------------- f32 -> bf16 (optionally pitched dest) ----------------
__global__ void k_conv(const float* __restrict__ src, unsigned short* __restrict__ dst,
                       long n, int cols, int dstld)
{
    long stride = (long)gridDim.x * 256;
    for (long i = (long)blockIdx.x * 256 + threadIdx.x; i < n; i += stride) {
        if (cols == dstld) {
            dst[i] = f2bf(src[i]);
        } else {
            long r = i / cols;
            int c = (int)(i - r * cols);
            dst[r * (long)dstld + c] = f2bf(src[i]);
        }
    }
}

// ---------------- gather+convert enc (sorted) ----------------
__global__ void k_encsort(const float* __restrict__ enc, const int* __restrict__ order,
                          unsigned short* __restrict__ enc_s)
{
    int p = blockIdx.x, b = blockIdx.y;
    int src = order[b];
    const float* s = enc + ((size_t)src * NP + p) * NENC + threadIdx.x * 8;
    unsigned short* d = enc_s + ((size_t)b * NP + p) * NENC + threadIdx.x * 8;
    float4 v0 = *(const float4*)s;
    float4 v1 = *(const float4*)(s + 4);
    uint4 o;
    o.x = (unsigned)f2bf(v0.x) | ((unsigned)f2bf(v0.y) << 16);
    o.y = (unsigned)f2bf(v0.z) | ((unsigned)f2bf(v0.w) << 16);
    o.z = (unsigned)f2bf(v1.x) | ((unsigned)f2bf(v1.y) << 16);
    o.w = (unsigned)f2bf(v1.z) | ((unsigned)f2bf(v1.w) << 16);
    *(uint4*)d = o;
}

// ---------------- mean over pixels ----------------
__global__ void k_mean(const unsigned short* __restrict__ enc_s, unsigned short* __restrict__ meanb)
{
    int c = blockIdx.x * 256 + threadIdx.x;
    int b = blockIdx.y;
    const unsigned short* e = enc_s + (size_t)b * NP * NENC + c;
    float s = 0.f;
    for (int p = 0; p < NP; p++) s += bf2f(e[(size_t)p * NENC]);
    meanb[(size_t)b * NENC + c] = f2bf(s * (1.f / NP));
}

// ---------------- init h,c from hc0 ----------------
__global__ void k_init(const float* __restrict__ hc0, unsigned short* __restrict__ inp,
                       float* __restrict__ cst)
{
    int b = blockIdx.x;
    for (int j = threadIdx.x; j < NH; j += 256) {
        inp[(size_t)b * NIN + (NE + NENC) + j] = f2bf(hc0[(size_t)b * 1024 + j]);
        cst[(size_t)b * NH + j] = hc0[(size_t)b * 1024 + NH + j];
    }
}

// ---------------- generic MFMA GEMM: C = A(MxK) @ B(NxK)^T + bias ----------------
// A,B bf16 row-major (K-contiguous); C f32 or bf16; optional active-row limit.
template<bool BF16_OUT>
__global__ __launch_bounds__(256)
void gemm_bt(const __bf16* __restrict__ A, int lda,
             const __bf16* __restrict__ Bw, int ldb,
             void* __restrict__ Cp, long ldc,
             const float* __restrict__ bias,
             int M, int N, int K,
             const int* __restrict__ limit_ptr)
{
    int m0 = blockIdx.y * 64;
    int limit = M;
    if (limit_ptr) { limit = *limit_ptr; if (limit > M) limit = M; }
    if (m0 >= limit) return;
    int n0 = blockIdx.x * 64;

    __shared__ __align__(16) __bf16 sA[64 * 32];
    __shared__ __align__(16) __bf16 sB[64 * 32];

    int tid  = threadIdx.x;
    int lane = tid & 63;
    int wv   = tid >> 6;
    int wm   = wv >> 1, wn = wv & 1;

    int sr  = tid >> 2;          // staging row in tile
    int scb = tid & 3;           // staging col-block (8 elems)
    int swz = scb ^ (sr & 3);    // XOR bank swizzle

    const __bf16* aSrc = A + (size_t)(m0 + sr) * lda + scb * 8;
    int bn = n0 + sr; if (bn > N - 1) bn = N - 1;
    const __bf16* bSrc = Bw + (size_t)bn * ldb + scb * 8;
    __bf16* aDst = &sA[sr * 32 + swz * 8];
    __bf16* bDst = &sB[sr * 32 + swz * 8];

    int fr = lane & 15;
    int kb = lane >> 4;

    f32x4 acc[2][2] = {};

    for (int k0 = 0; k0 < K; k0 += 32) {
        uint4 av = *(const uint4*)(aSrc + k0);
        uint4 bv = *(const uint4*)(bSrc + k0);
        __syncthreads();
        *(uint4*)aDst = av;
        *(uint4*)bDst = bv;
        __syncthreads();
        bf16x8 af[2], bfr[2];
        #pragma unroll
        for (int m = 0; m < 2; m++) {
            int r = wm * 32 + m * 16 + fr;
            af[m] = *(const bf16x8*)&sA[r * 32 + ((kb ^ (r & 3)) * 8)];
        }
        #pragma unroll
        for (int n = 0; n < 2; n++) {
            int r = wn * 32 + n * 16 + fr;
            bfr[n] = *(const bf16x8*)&sB[r * 32 + ((kb ^ (r & 3)) * 8)];
        }
        #pragma unroll
        for (int m = 0; m < 2; m++)
            #pragma unroll
            for (int n = 0; n < 2; n++)
                acc[m][n] = __builtin_amdgcn_mfma_f32_16x16x32_bf16(af[m], bfr[n], acc[m][n], 0, 0, 0);
    }

    int rbase = m0 + wm * 32;
    int cbase = n0 + wn * 32;
    #pragma unroll
    for (int m = 0; m < 2; m++) {
        #pragma unroll
        for (int n = 0; n < 2; n++) {
            int col = cbase + n * 16 + (lane & 15);
            if (col >= N) continue;
            float bsv = bias ? bias[col] : 0.f;
            #pragma unroll
            for (int r4 = 0; r4 < 4; r4++) {
                int row = rbase + m * 16 + (lane >> 4) * 4 + r4;
                if (row < limit) {
                    float v = acc[m][n][r4] + bsv;
                    if (BF16_OUT)
                        ((unsigned short*)Cp)[(size_t)row * ldc + col] = f2bf(v);
                    else
                        ((float*)Cp)[(size_t)row * ldc + col] = v;
                }
            }
        }
    }
}

// ---------------- fused attention step ----------------
// per block b: e = relu(enc_att+hid_att)@f_w+f_b; softmax; ctx = alpha@enc;
// ctx *= sigmoid(sag_pre); write ctx bf16 into inp; also gather x_t embedding.
__global__ __launch_bounds__(256)
void k_attn(const unsigned short* __restrict__ enc_s, const unsigned short* __restrict__ enc_att,
            const float* __restrict__ hs_out, const float* __restrict__ att_fw,
            const float* __restrict__ att_fb, const int* __restrict__ caps_s,
            const float* __restrict__ emb, unsigned short* __restrict__ inp,
            const int* __restrict__ act_cnt, int t)
{
    int b = blockIdx.x;
    if (b >= act_cnt[t]) return;
    int tid = threadIdx.x, lane = tid & 63, wv = tid >> 6;

    __shared__ float hid[NE];
    __shared__ float fw[NE];
    __shared__ float sm[200];
    __shared__ float red[2];

    const float* hrow = hs_out + (size_t)b * NHS;
    for (int i = tid; i < NE; i += 256) { hid[i] = hrow[i]; fw[i] = att_fw[i]; }

    // x_t embedding gather (bf16 pair store)
    {
        int tok = caps_s[b * NS + t];
        const float* er = emb + (size_t)tok * NE;
        int i = tid * 2;
        unsigned v = (unsigned)f2bf(er[i]) | ((unsigned)f2bf(er[i + 1]) << 16);
        *(unsigned*)&inp[(size_t)b * NIN + i] = v;
    }
    __syncthreads();

    float fb = att_fb[0];
    const unsigned short* ea = enc_att + (size_t)b * NP * NE + lane * 8;
    int a0 = lane * 8;
    for (int p = wv; p < NP; p += 4) {
        uint4 u = *(const uint4*)(ea + (size_t)p * NE);
        float s = 0.f, v;
        v = bf_lo(u.x) + hid[a0 + 0]; if (v > 0.f) s += v * fw[a0 + 0];
        v = bf_hi(u.x) + hid[a0 + 1]; if (v > 0.f) s += v * fw[a0 + 1];
        v = bf_lo(u.y) + hid[a0 + 2]; if (v > 0.f) s += v * fw[a0 + 2];
        v = bf_hi(u.y) + hid[a0 + 3]; if (v > 0.f) s += v * fw[a0 + 3];
        v = bf_lo(u.z) + hid[a0 + 4]; if (v > 0.f) s += v * fw[a0 + 4];
        v = bf_hi(u.z) + hid[a0 + 5]; if (v > 0.f) s += v * fw[a0 + 5];
        v = bf_lo(u.w) + hid[a0 + 6]; if (v > 0.f) s += v * fw[a0 + 6];
        v = bf_hi(u.w) + hid[a0 + 7]; if (v > 0.f) s += v * fw[a0 + 7];
        for (int off = 32; off; off >>= 1) s += __shfl_down(s, off);
        if (lane == 0) sm[p] = s + fb;
    }
    __syncthreads();

    if (wv == 0) {
        float mx = -3e38f;
        for (int p = lane; p < NP; p += 64) mx = fmaxf(mx, sm[p]);
        for (int off = 32; off; off >>= 1) mx = fmaxf(mx, __shfl_down(mx, off));
        mx = __shfl(mx, 0);
        float ss = 0.f;
        for (int p = lane; p < NP; p += 64) ss += __expf(sm[p] - mx);
        for (int off = 32; off; off >>= 1) ss += __shfl_down(ss, off);
        if (lane == 0) { red[0] = mx; red[1] = ss; }
    }
    __syncthreads();
    float mx = red[0], inv = 1.f / red[1];
    for (int p = tid; p < NP; p += 256) sm[p] = __expf(sm[p] - mx) * inv;
    __syncthreads();

    // ctx = sum_p alpha[p] * enc[b][p][:]
    const unsigned short* eb = enc_s + (size_t)b * NP * NENC + tid * 8;
    float acc[8] = {0.f, 0.f, 0.f, 0.f, 0.f, 0.f, 0.f, 0.f};
    #pragma unroll 2
    for (int p = 0; p < NP; p++) {
        float w = sm[p];
        uint4 u = *(const uint4*)(eb + (size_t)p * NENC);
        acc[0] += w * bf_lo(u.x); acc[1] += w * bf_hi(u.x);
        acc[2] += w * bf_lo(u.y); acc[3] += w * bf_hi(u.y);
        acc[4] += w * bf_lo(u.z); acc[5] += w * bf_hi(u.z);
        acc[6] += w * bf_lo(u.w); acc[7] += w * bf_hi(u.w);
    }
    const float* sp = hs_out + (size_t)b * NHS + NH + tid * 8;
    unsigned short* op = inp + (size_t)b * NIN + NE + tid * 8;
    uint4 o;
    unsigned ow[4];
    #pragma unroll
    for (int i = 0; i < 4; i++) {
        float g0 = sigf(sp[2 * i]);
        float g1 = sigf(sp[2 * i + 1]);
        ow[i] = (unsigned)f2bf(acc[2 * i] * g0) | ((unsigned)f2bf(acc[2 * i + 1] * g1) << 16);
    }
    o.x = ow[0]; o.y = ow[1]; o.z = ow[2]; o.w = ow[3];
    *(uint4*)op = o;
}

// ---------------- LSTM pointwise ----------------
__global__ void k_lstm(const float* __restrict__ gates, float* __restrict__ cst,
                       unsigned short* __restrict__ inp, const int* __restrict__ act_cnt, int t)
{
    int b = blockIdx.x;
    if (b >= act_cnt[t]) return;
    const float* g = gates + (size_t)b * NG;
    for (int idx = threadIdx.x; idx < NH; idx += 256) {
        float i_ = sigf(g[idx]);
        float f_ = sigf(g[NH + idx]);
        float gg = tanhf(g[2 * NH + idx]);
        float o_ = sigf(g[3 * NH + idx]);
        float cn = f_ * cst[(size_t)b * NH + idx] + i_ * gg;
        cst[(size_t)b * NH + idx] = cn;
        float hn = o_ * tanhf(cn);
        inp[(size_t)b * NIN + (NE + NENC) + idx] = f2bf(hn);
    }
}

// ---------------- host ----------------
extern "C" void kernel_launch(void* const* d_in, const int* in_sizes, int n_in,
                              void* d_out, int out_size, void* d_ws, size_t ws_size,
                              hipStream_t stream)
{
    const float* enc_img  = (const float*)d_in[0];
    const int*   captions = (const int*)d_in[1];
    const int*   cap_len  = (const int*)d_in[2];
    const float* emb      = (const float*)d_in[3];
    const float* W_ih     = (const float*)d_in[4];
    const float* W_hh     = (const float*)d_in[5];
    const float* b_ih     = (const float*)d_in[6];
    const float* b_hh     = (const float*)d_in[7];
    const float* ec_w     = (const float*)d_in[8];
    const float* ec_b     = (const float*)d_in[9];
    const float* eh_w     = (const float*)d_in[10];
    const float* eh_b     = (const float*)d_in[11];
    const float* sag_w    = (const float*)d_in[12];
    const float* sag_b    = (const float*)d_in[13];
    const float* att_e_w  = (const float*)d_in[14];
    const float* att_e_b  = (const float*)d_in[15];
    const float* att_h_w  = (const float*)d_in[16];
    const float* att_h_b  = (const float*)d_in[17];
    const float* att_f_w  = (const float*)d_in[18];
    const float* att_f_b  = (const float*)d_in[19];
    const float* fc_w     = (const float*)d_in[20];
    const float* fc_b     = (const float*)d_in[21];
    float* out = (float*)d_out;

    char* ws = (char*)d_ws;
    size_t off = 0;
    auto alloc = [&](size_t bytes) -> char* {
        char* r = ws + off;
        off += (bytes + 255) & ~(size_t)255;
        return r;
    };
    int* order   = (int*)alloc(NB * 4);
    int* act     = (int*)alloc(64 * 4);
    int* caps_s  = (int*)alloc((size_t)NB * NS * 4);
    float* bg    = (float*)alloc(NG * 4);
    float* hsb   = (float*)alloc(NHS * 4);
    float* hcb   = (float*)alloc(1024 * 4);
    unsigned short* attew = (unsigned short*)alloc((size_t)NE * NENC * 2);
    unsigned short* hsw   = (unsigned short*)alloc((size_t)NHS * NH * 2);
    unsigned short* wcat  = (unsigned short*)alloc((size_t)NG * NIN * 2);
    unsigned short* fcw   = (unsigned short*)alloc((size_t)NV * NH * 2);
    unsigned short* hcw   = (unsigned short*)alloc((size_t)1024 * NENC * 2);
    unsigned short* meanb = (unsigned short*)alloc((size_t)NB * NENC * 2);
    float* hc0   = (float*)alloc((size_t)NB * 1024 * 4);
    float* hsout = (float*)alloc((size_t)NB * NHS * 4);
    float* gates = (float*)alloc((size_t)NB * NG * 4);
    unsigned short* inp = (unsigned short*)alloc((size_t)NB * NIN * 2);
    float* cst   = (float*)alloc((size_t)NB * NH * 4);
    unsigned short* encs   = (unsigned short*)alloc((size_t)NB * NP * NENC * 2);
    unsigned short* encatt = (unsigned short*)alloc((size_t)NB * NP * NE * 2);

    // zero all outputs (preds inactive rows + coefs must be 0)
    hipMemsetAsync(d_out, 0, (size_t)out_size * 4, stream);

    k_sort<<<1, 256, 0, stream>>>(cap_len, captions, order, act, caps_s, out, out + NB);
    k_bias<<<10, 256, 0, stream>>>(b_ih, b_hh, att_h_b, sag_b, eh_b, ec_b, bg, hsb, hcb);

    k_conv<<<1024, 256, 0, stream>>>(att_e_w, attew, (long)NE * NENC, NENC, NENC);
    k_conv<<<256, 256, 0, stream>>>(att_h_w, hsw, (long)NH * NE, NE, NE);
    k_conv<<<1024, 256, 0, stream>>>(sag_w, hsw + (size_t)NH * NE, (long)NENC * NH, NH, NH);
    k_conv<<<2048, 256, 0, stream>>>(W_ih, wcat, (long)NG * (NE + NENC), NE + NENC, NIN);
    k_conv<<<1024, 256, 0, stream>>>(W_hh, wcat + (NE + NENC), (long)NG * NH, NH, NIN);
    k_conv<<<2048, 256, 0, stream>>>(fc_w, fcw, (long)NV * NH, NH, NH);
    k_conv<<<1024, 256, 0, stream>>>(eh_w, hcw, (long)NH * NENC, NENC, NENC);
    k_conv<<<1024, 256, 0, stream>>>(ec_w, hcw + (size_t)NH * NENC, (long)NH * NENC, NENC, NENC);

    k_encsort<<<dim3(NP, NB), 256, 0, stream>>>(enc_img, order, encs);
    k_mean<<<dim3(8, NB), 256, 0, stream>>>(encs, meanb);

    // h0,c0 = mean_enc @ [eh_w; ec_w]^T + [eh_b; ec_b]
    gemm_bt<false><<<dim3(16, 4), 256, 0, stream>>>(
        (const __bf16*)meanb, NENC, (const __bf16*)hcw, NENC,
        hc0, 1024, hcb, NB, 1024, NENC, nullptr);
    k_init<<<NB, 256, 0, stream>>>(hc0, inp, cst);

    // enc_att = enc @ att_e_w^T + att_e_b  (bf16 out)
    gemm_bt<true><<<dim3(8, 784), 256, 0, stream>>>(
        (const __bf16*)encs, NENC, (const __bf16*)attew, NENC,
        encatt, NE, att_e_b, NB * NP, NE, NENC, nullptr);

    float* preds = out + NB + NB * NS;  // 256 + 13824 = 14080
    for (int t = 0; t < NT; t++) {
        // [hid_att | sag_pre] = h @ [att_h_w; sag_w]^T + [att_h_b; sag_b]
        gemm_bt<false><<<dim3(40, 4), 256, 0, stream>>>(
            (const __bf16*)inp + (NE + NENC), NIN, (const __bf16*)hsw, NH,
            hsout, NHS, hsb, NB, NHS, NH, act + t);
        k_attn<<<NB, 256, 0, stream>>>(encs, encatt, hsout, att_f_w, att_f_b,
                                       caps_s, emb, inp, act, t);
        // gates = [x|ctx|h] @ [W_ih|W_hh]^T + (b_ih+b_hh)
        gemm_bt<false><<<dim3(32, 4), 256, 0, stream>>>(
            (const __bf16*)inp, NIN, (const __bf16*)wcat, NIN,
            gates, NG, bg, NB, NG, NIN, act + t);
        k_lstm<<<NB, 256, 0, stream>>>(gates, cst, inp, act, t);
        // logits = h_new @ fc_w^T + fc_b  -> preds[b][t][:]
        gemm_bt<false><<<dim3(157, 4), 256, 0, stream>>>(
            (const __bf16*)inp + (NE + NENC), NIN, (const __bf16*)fcw, NH,
            preds + (size_t)t * NV, (long)NT * NV, fc_b, NB, NV, NH, act + t);
    }
}